// Round 1
// baseline (346.903 us; speedup 1.0000x reference)
//
#include <hip/hip_runtime.h>

// SDGCN fused: per (b,t): S=X·X^T, online-softmax, A-mask, H=(A*P/Z*c_a)·X,
// relu(H·W^T)*c_b, LayerNorm, +X residual. bf16 MFMA (16x16x32), fp32 everywhere else.
// B=4,T=16 -> BT=64; N=1024; D=128.

#define NNODES 1024
#define DDIM   128
#define BROWS  64            // rows per block
#define WROWS  16            // rows per wave
#define MC     64            // m-chunk
#define NCHUNK (NNODES / MC) // 16
#define THREADS 256

#define CA 0.08838834764831845f   // 1/sqrt(128+1e-8)
#define CB 0.08838834764831845f   // 1/sqrt(128+1e-9)
#define LN_EPS 1e-5f

typedef __attribute__((ext_vector_type(8))) short bf16x8;
typedef __attribute__((ext_vector_type(4))) float f32x4;

// LDS layout (ushort units)
#define XBF_S 136                 // Xbf[64][136]  bf16 row-major chunk (pad: 2-way banks)
#define XBT_S 72                  // XbT[128][72]  bf16 transposed chunk
#define P_S   72                  // P per wave [16][72]
#define H_S   136                 // h per wave [16][136] (reuses XbT region)
#define XBF_OFF 0                 // 8704 ushorts
#define XBT_OFF 8704              // 9216 ushorts
#define P_OFF   17920             // 4*16*72 = 4608 ushorts
#define SM_TOT  22528             // 45056 bytes

__device__ __forceinline__ unsigned short f2bf(float f) {
  unsigned int u = __float_as_uint(f);
  u += 0x7FFFu + ((u >> 16) & 1u);     // RNE
  return (unsigned short)(u >> 16);
}

__device__ __forceinline__ bf16x8 pack8(float4 a, float4 b) {
  union { bf16x8 v; unsigned short u[8]; } pk;
  pk.u[0] = f2bf(a.x); pk.u[1] = f2bf(a.y); pk.u[2] = f2bf(a.z); pk.u[3] = f2bf(a.w);
  pk.u[4] = f2bf(b.x); pk.u[5] = f2bf(b.y); pk.u[6] = f2bf(b.z); pk.u[7] = f2bf(b.w);
  return pk.v;
}

__global__ __launch_bounds__(THREADS, 2)
void sdgcn_fused(const float* __restrict__ X, const float* __restrict__ A,
                 const float* __restrict__ W, const float* __restrict__ gamma,
                 const float* __restrict__ beta, float* __restrict__ Out) {
  const int bt   = blockIdx.y;
  const int row0 = blockIdx.x * BROWS;
  const int tid  = (int)threadIdx.x;
  const int wid  = tid >> 6;      // wave id 0..3
  const int lane = tid & 63;
  const int c    = lane & 15;     // 16-dim index within MFMA tile
  const int q    = lane >> 4;     // quad 0..3

  const float* Xbt = X + (size_t)bt * NNODES * DDIM;

  __shared__ __align__(16) unsigned short sm[SM_TOT];
  unsigned short* Pw = sm + P_OFF + wid * (WROWS * P_S);

  // ---- Q A-fragments, persistent in regs. A-layout: A[i=lane&15][k=quad*8+j] ----
  bf16x8 qfrag[4];
  {
    const float* qrow = Xbt + (size_t)(row0 + wid * WROWS + c) * DDIM;
#pragma unroll
    for (int ds = 0; ds < 4; ++ds) {
      const float* p = qrow + ds * 32 + q * 8;
      float4 a = *(const float4*)p;
      float4 b = *(const float4*)(p + 4);
      qfrag[ds] = pack8(a, b);
    }
  }

  // online-softmax state per row (rows 4q..4q+3 via reg index, replicated over 16 c-lanes)
  float m_st[4], z_st[4];
#pragma unroll
  for (int r = 0; r < 4; ++r) { m_st[r] = -__builtin_inff(); z_st[r] = 0.f; }
  f32x4 Ofr[8];   // O accumulator, C/D layout: row=4q+reg, col=dt*16+c
#pragma unroll
  for (int dt = 0; dt < 8; ++dt) Ofr[dt] = (f32x4){0.f, 0.f, 0.f, 0.f};

  const int grow = row0 + wid * WROWS + q * 4;   // +r gives global row for C/D-layout values

  for (int ch = 0; ch < NCHUNK; ++ch) {
    const int m0 = ch * MC;
    // ---- stage chunk -> Xbf bf16 row-major (coalesced fp32 float4 loads) ----
#pragma unroll
    for (int k = 0; k < 8; ++k) {
      int idx = tid + k * 256;               // 2048 float4s = 64x128
      int m = idx >> 5, d4 = idx & 31;
      float4 v = *(const float4*)(Xbt + (size_t)(m0 + m) * DDIM + d4 * 4);
      unsigned int lo = (unsigned int)f2bf(v.x) | ((unsigned int)f2bf(v.y) << 16);
      unsigned int hi = (unsigned int)f2bf(v.z) | ((unsigned int)f2bf(v.w) << 16);
      *(uint2*)(sm + XBF_OFF + m * XBF_S + d4 * 4) = make_uint2(lo, hi);
    }
    __syncthreads();   // Xbf ready; also fences prev-iter PV reads of XbT before rebuild
    // ---- build XbT[d][m] from Xbf (b16 column reads are conflict-free, b128 writes) ----
#pragma unroll
    for (int k = 0; k < 4; ++k) {
      int task = tid + k * 256;              // 1024 tasks = 128 d x 8 m-octets
      int d = task & 127, m8 = task >> 7;
      int base = XBF_OFF + d;
      unsigned int w0 = (unsigned int)sm[base + (m8*8+0)*XBF_S] | ((unsigned int)sm[base + (m8*8+1)*XBF_S] << 16);
      unsigned int w1 = (unsigned int)sm[base + (m8*8+2)*XBF_S] | ((unsigned int)sm[base + (m8*8+3)*XBF_S] << 16);
      unsigned int w2 = (unsigned int)sm[base + (m8*8+4)*XBF_S] | ((unsigned int)sm[base + (m8*8+5)*XBF_S] << 16);
      unsigned int w3 = (unsigned int)sm[base + (m8*8+6)*XBF_S] | ((unsigned int)sm[base + (m8*8+7)*XBF_S] << 16);
      *(uint4*)(sm + XBT_OFF + d * XBT_S + m8 * 8) = make_uint4(w0, w1, w2, w3);
    }
    // ---- scores: S[16 rows][64 m] per wave; B[k=d][j=m] = Xbf row-reads ----
    f32x4 S[4];
#pragma unroll
    for (int mt = 0; mt < 4; ++mt) {
      f32x4 acc = (f32x4){0.f, 0.f, 0.f, 0.f};
#pragma unroll
      for (int ds = 0; ds < 4; ++ds) {
        bf16x8 bf = *(const bf16x8*)(sm + XBF_OFF + (mt*16 + c) * XBF_S + ds*32 + q*8);
        acc = __builtin_amdgcn_mfma_f32_16x16x32_bf16(qfrag[ds], bf, acc, 0, 0, 0);
      }
      S[mt] = acc;
    }
    __syncthreads();   // XbT complete before PV reads
    // ---- online softmax (reduce over m = 4 tiles in-reg + 16 c-lanes via shfl) ----
    float alpha[4];
#pragma unroll
    for (int r = 0; r < 4; ++r) {
      float mx = fmaxf(fmaxf(S[0][r], S[1][r]), fmaxf(S[2][r], S[3][r]));
#pragma unroll
      for (int off = 1; off < 16; off <<= 1) mx = fmaxf(mx, __shfl_xor(mx, off, 64));
      float mnew = fmaxf(m_st[r], mx);
      float al = __expf(m_st[r] - mnew);     // 0 on first chunk (m_st=-inf)
      alpha[r] = al;
      m_st[r] = mnew;
      float zs = 0.f;
#pragma unroll
      for (int mt = 0; mt < 4; ++mt) {
        float p = __expf(S[mt][r] - mnew);
        S[mt][r] = p;
        zs += p;
      }
#pragma unroll
      for (int off = 1; off < 16; off <<= 1) zs += __shfl_xor(zs, off, 64);
      z_st[r] = z_st[r] * al + zs;           // Z is over raw softmax (unmasked), per reference
    }
    // ---- adjacency mask (A read direct from global, L2-resident), write P bf16 ----
#pragma unroll
    for (int r = 0; r < 4; ++r) {
#pragma unroll
      for (int mt = 0; mt < 4; ++mt) {
        float av = A[(size_t)(grow + r) * NNODES + m0 + mt*16 + c];
        Pw[(q*4 + r) * P_S + mt*16 + c] = f2bf(S[mt][r] * av);
      }
    }
    // ---- rescale O by alpha ----
#pragma unroll
    for (int dt = 0; dt < 8; ++dt) {
      Ofr[dt][0] *= alpha[0]; Ofr[dt][1] *= alpha[1];
      Ofr[dt][2] *= alpha[2]; Ofr[dt][3] *= alpha[3];
    }
    // ---- PV: O += P·Xchunk ; A=P from Pw rows (lane&15=row), B[k=m][j=d] from XbT ----
#pragma unroll
    for (int ks = 0; ks < 2; ++ks) {
      bf16x8 pf = *(const bf16x8*)(Pw + c * P_S + ks*32 + q*8);
#pragma unroll
      for (int dt = 0; dt < 8; ++dt) {
        bf16x8 vf = *(const bf16x8*)(sm + XBT_OFF + (dt*16 + c) * XBT_S + ks*32 + q*8);
        Ofr[dt] = __builtin_amdgcn_mfma_f32_16x16x32_bf16(pf, vf, Ofr[dt], 0, 0, 0);
      }
    }
  }

  __syncthreads();   // all PV reads done; reuse XbT region for h
  // ---- h = (CA/z)*O -> bf16, per-wave LDS round-trip into A-layout ----
  unsigned short* Hw = sm + XBT_OFF + wid * (WROWS * H_S);
#pragma unroll
  for (int r = 0; r < 4; ++r) {
    float rinv = CA / z_st[r];
#pragma unroll
    for (int dt = 0; dt < 8; ++dt)
      Hw[(q*4 + r) * H_S + dt*16 + c] = f2bf(Ofr[dt][r] * rinv);
  }
  // ---- G = h·W^T via MFMA; B[k=d][j] = W row-reads direct from global (d-contiguous) ----
  f32x4 G[8];
#pragma unroll
  for (int jt = 0; jt < 8; ++jt) G[jt] = (f32x4){0.f, 0.f, 0.f, 0.f};
#pragma unroll
  for (int ks = 0; ks < 4; ++ks) {
    bf16x8 hf = *(const bf16x8*)(Hw + c * H_S + ks*32 + q*8);
#pragma unroll
    for (int jt = 0; jt < 8; ++jt) {
      const float* wr = W + (size_t)(jt*16 + c) * DDIM + ks*32 + q*8;
      float4 a = *(const float4*)wr;
      float4 b = *(const float4*)(wr + 4);
      bf16x8 wf = pack8(a, b);
      G[jt] = __builtin_amdgcn_mfma_f32_16x16x32_bf16(hf, wf, G[jt], 0, 0, 0);
    }
  }
  // relu + output scale
#pragma unroll
  for (int jt = 0; jt < 8; ++jt) {
#pragma unroll
    for (int r = 0; r < 4; ++r) G[jt][r] = fmaxf(G[jt][r], 0.f) * CB;
  }
  // ---- LayerNorm over j (in-reg jt sum + 16-lane shfl), + residual, store ----
  float* Obt = Out + (size_t)bt * NNODES * DDIM;
#pragma unroll
  for (int r = 0; r < 4; ++r) {
    float s1 = 0.f, s2 = 0.f;
#pragma unroll
    for (int jt = 0; jt < 8; ++jt) { float v = G[jt][r]; s1 += v; s2 += v * v; }
#pragma unroll
    for (int off = 1; off < 16; off <<= 1) {
      s1 += __shfl_xor(s1, off, 64);
      s2 += __shfl_xor(s2, off, 64);
    }
    float mu = s1 * (1.f / 128.f);
    float va = s2 * (1.f / 128.f) - mu * mu;
    float rs = rsqrtf(va + LN_EPS);
    const float* xr = Xbt + (size_t)(grow + r) * DDIM;
    float* orow = Obt + (size_t)(grow + r) * DDIM;
#pragma unroll
    for (int jt = 0; jt < 8; ++jt) {
      int col = jt * 16 + c;
      orow[col] = (G[jt][r] - mu) * rs * gamma[col] + beta[col] + xr[col];
    }
  }
}

extern "C" void kernel_launch(void* const* d_in, const int* in_sizes, int n_in,
                              void* d_out, int out_size, void* d_ws, size_t ws_size,
                              hipStream_t stream) {
  const float* X     = (const float*)d_in[0];
  const float* A     = (const float*)d_in[1];
  const float* W     = (const float*)d_in[2];
  const float* gamma = (const float*)d_in[3];
  const float* beta  = (const float*)d_in[4];
  float* Out = (float*)d_out;
  dim3 grid(NNODES / BROWS, 64);   // 16 row-blocks x 64 (b,t)
  hipLaunchKernelGGL(sdgcn_fused, grid, dim3(THREADS), 0, stream, X, A, W, gamma, beta, Out);
}

// Round 2
// 209.926 us; speedup vs baseline: 1.6525x; 1.6525x over previous
//
#include <hip/hip_runtime.h>

// SDGCN fused: per (b,t): S=X·X^T, online-softmax, A-mask, H=(A*P/Z*c_a)·X,
// relu(H·W^T)*c_b, LayerNorm, +X residual. bf16 MFMA (16x16x32), fp32 elsewhere.
// B=4,T=16 -> BT=64; N=1024; D=128.
// R2: 512-thread blocks (8 waves, 128 rows) -> 2 blocks/CU, 16 waves/CU (~49% occ),
//     staging+transpose amortized over 8 waves; A-mask prefetched before softmax.

#define NNODES 1024
#define DDIM   128
#define BROWS  128           // rows per block
#define WROWS  16            // rows per wave
#define MC     64            // m-chunk
#define NCHUNK (NNODES / MC) // 16
#define THREADS 512

#define CA 0.08838834764831845f   // 1/sqrt(128+1e-8)
#define CB 0.08838834764831845f   // 1/sqrt(128+1e-9)
#define LN_EPS 1e-5f

typedef __attribute__((ext_vector_type(8))) short bf16x8;
typedef __attribute__((ext_vector_type(4))) float f32x4;

// LDS layout (ushort units)
#define XBF_S 136                 // Xbf[64][136]  bf16 row-major chunk (stride 17x16B: conflict-benign)
#define XBT_S 72                  // XbT[128][72]  bf16 transposed chunk (stride 9x16B)
#define P_S   72                  // P per wave [16][72]
#define H_S   136                 // h per wave [16][136] (reuses XbT+P region post-loop)
#define XBF_OFF 0                 // 64*136  = 8704 ushorts
#define XBT_OFF 8704              // 128*72  = 9216 ushorts
#define P_OFF   17920             // 8*16*72 = 9216 ushorts
#define SM_TOT  27136             // 54272 bytes -> 2 blocks/CU

__device__ __forceinline__ unsigned short f2bf(float f) {
  unsigned int u = __float_as_uint(f);
  u += 0x7FFFu + ((u >> 16) & 1u);     // RNE
  return (unsigned short)(u >> 16);
}

__device__ __forceinline__ bf16x8 pack8(float4 a, float4 b) {
  union { bf16x8 v; unsigned short u[8]; } pk;
  pk.u[0] = f2bf(a.x); pk.u[1] = f2bf(a.y); pk.u[2] = f2bf(a.z); pk.u[3] = f2bf(a.w);
  pk.u[4] = f2bf(b.x); pk.u[5] = f2bf(b.y); pk.u[6] = f2bf(b.z); pk.u[7] = f2bf(b.w);
  return pk.v;
}

__global__ __launch_bounds__(THREADS, 4)   // 4 waves/SIMD = 2 blocks/CU
void sdgcn_fused(const float* __restrict__ X, const float* __restrict__ A,
                 const float* __restrict__ W, const float* __restrict__ gamma,
                 const float* __restrict__ beta, float* __restrict__ Out) {
  const int bt   = blockIdx.y;
  const int row0 = blockIdx.x * BROWS;
  const int tid  = (int)threadIdx.x;
  const int wid  = tid >> 6;      // wave id 0..7
  const int lane = tid & 63;
  const int c    = lane & 15;     // 16-dim index within MFMA tile
  const int q    = lane >> 4;     // quad 0..3

  const float* Xbt = X + (size_t)bt * NNODES * DDIM;

  __shared__ __align__(16) unsigned short sm[SM_TOT];
  unsigned short* Pw = sm + P_OFF + wid * (WROWS * P_S);

  // ---- Q A-fragments, persistent in regs. A-layout: A[i=lane&15][k=quad*8+j] ----
  bf16x8 qfrag[4];
  {
    const float* qrow = Xbt + (size_t)(row0 + wid * WROWS + c) * DDIM;
#pragma unroll
    for (int ds = 0; ds < 4; ++ds) {
      const float* p = qrow + ds * 32 + q * 8;
      float4 a = *(const float4*)p;
      float4 b = *(const float4*)(p + 4);
      qfrag[ds] = pack8(a, b);
    }
  }

  // online-softmax state per row (rows 4q..4q+3 via reg index, replicated over 16 c-lanes)
  float m_st[4], z_st[4];
#pragma unroll
  for (int r = 0; r < 4; ++r) { m_st[r] = -__builtin_inff(); z_st[r] = 0.f; }
  f32x4 Ofr[8];   // O accumulator, C/D layout: row=4q+reg, col=dt*16+c
#pragma unroll
  for (int dt = 0; dt < 8; ++dt) Ofr[dt] = (f32x4){0.f, 0.f, 0.f, 0.f};

  const int grow = row0 + wid * WROWS + q * 4;   // +r gives global row for C/D-layout values

  for (int ch = 0; ch < NCHUNK; ++ch) {
    const int m0 = ch * MC;
    // ---- stage chunk -> Xbf bf16 row-major (coalesced fp32 float4 loads) ----
#pragma unroll
    for (int k = 0; k < 4; ++k) {
      int idx = tid + k * THREADS;           // 2048 float4s = 64x128
      int m = idx >> 5, d4 = idx & 31;
      float4 v = *(const float4*)(Xbt + (size_t)(m0 + m) * DDIM + d4 * 4);
      unsigned int lo = (unsigned int)f2bf(v.x) | ((unsigned int)f2bf(v.y) << 16);
      unsigned int hi = (unsigned int)f2bf(v.z) | ((unsigned int)f2bf(v.w) << 16);
      *(uint2*)(sm + XBF_OFF + m * XBF_S + d4 * 4) = make_uint2(lo, hi);
    }
    __syncthreads();   // Xbf ready; also fences prev-iter PV reads of XbT before rebuild
    // ---- build XbT[d][m] from Xbf (b16 column reads are 2-way/free, b128 writes) ----
#pragma unroll
    for (int k = 0; k < 2; ++k) {
      int task = tid + k * THREADS;          // 1024 tasks = 128 d x 8 m-octets
      int d = task & 127, m8 = task >> 7;
      int base = XBF_OFF + d;
      unsigned int w0 = (unsigned int)sm[base + (m8*8+0)*XBF_S] | ((unsigned int)sm[base + (m8*8+1)*XBF_S] << 16);
      unsigned int w1 = (unsigned int)sm[base + (m8*8+2)*XBF_S] | ((unsigned int)sm[base + (m8*8+3)*XBF_S] << 16);
      unsigned int w2 = (unsigned int)sm[base + (m8*8+4)*XBF_S] | ((unsigned int)sm[base + (m8*8+5)*XBF_S] << 16);
      unsigned int w3 = (unsigned int)sm[base + (m8*8+6)*XBF_S] | ((unsigned int)sm[base + (m8*8+7)*XBF_S] << 16);
      *(uint4*)(sm + XBT_OFF + d * XBT_S + m8 * 8) = make_uint4(w0, w1, w2, w3);
    }
    // ---- scores: S[16 rows][64 m] per wave; B[k=d][j=m] = Xbf row-reads ----
    f32x4 S[4];
#pragma unroll
    for (int mt = 0; mt < 4; ++mt) {
      f32x4 acc = (f32x4){0.f, 0.f, 0.f, 0.f};
#pragma unroll
      for (int ds = 0; ds < 4; ++ds) {
        bf16x8 bf = *(const bf16x8*)(sm + XBF_OFF + (mt*16 + c) * XBF_S + ds*32 + q*8);
        acc = __builtin_amdgcn_mfma_f32_16x16x32_bf16(qfrag[ds], bf, acc, 0, 0, 0);
      }
      S[mt] = acc;
    }
    // ---- prefetch adjacency values (global, L2-resident) to overlap softmax ----
    float av[4][4];
#pragma unroll
    for (int r = 0; r < 4; ++r)
#pragma unroll
      for (int mt = 0; mt < 4; ++mt)
        av[r][mt] = A[(size_t)(grow + r) * NNODES + m0 + mt*16 + c];
    __syncthreads();   // XbT complete before PV reads
    // ---- online softmax (reduce over m = 4 tiles in-reg + 16 c-lanes via shfl) ----
    float alpha[4];
#pragma unroll
    for (int r = 0; r < 4; ++r) {
      float mx = fmaxf(fmaxf(S[0][r], S[1][r]), fmaxf(S[2][r], S[3][r]));
#pragma unroll
      for (int off = 1; off < 16; off <<= 1) mx = fmaxf(mx, __shfl_xor(mx, off, 64));
      float mnew = fmaxf(m_st[r], mx);
      float al = __expf(m_st[r] - mnew);     // 0 on first chunk (m_st=-inf)
      alpha[r] = al;
      m_st[r] = mnew;
      float zs = 0.f;
#pragma unroll
      for (int mt = 0; mt < 4; ++mt) {
        float p = __expf(S[mt][r] - mnew);
        S[mt][r] = p;
        zs += p;
      }
#pragma unroll
      for (int off = 1; off < 16; off <<= 1) zs += __shfl_xor(zs, off, 64);
      z_st[r] = z_st[r] * al + zs;           // Z is over raw softmax (unmasked), per reference
    }
    // ---- adjacency mask, write P bf16 ----
#pragma unroll
    for (int r = 0; r < 4; ++r) {
#pragma unroll
      for (int mt = 0; mt < 4; ++mt)
        Pw[(q*4 + r) * P_S + mt*16 + c] = f2bf(S[mt][r] * av[r][mt]);
    }
    // ---- rescale O by alpha ----
#pragma unroll
    for (int dt = 0; dt < 8; ++dt) {
      Ofr[dt][0] *= alpha[0]; Ofr[dt][1] *= alpha[1];
      Ofr[dt][2] *= alpha[2]; Ofr[dt][3] *= alpha[3];
    }
    // ---- PV: O += P·Xchunk ; A=P from Pw rows (lane&15=row), B[k=m][j=d] from XbT ----
#pragma unroll
    for (int ks = 0; ks < 2; ++ks) {
      bf16x8 pf = *(const bf16x8*)(Pw + c * P_S + ks*32 + q*8);
#pragma unroll
      for (int dt = 0; dt < 8; ++dt) {
        bf16x8 vf = *(const bf16x8*)(sm + XBT_OFF + (dt*16 + c) * XBT_S + ks*32 + q*8);
        Ofr[dt] = __builtin_amdgcn_mfma_f32_16x16x32_bf16(pf, vf, Ofr[dt], 0, 0, 0);
      }
    }
  }

  __syncthreads();   // all PV reads done; reuse XbT+P region for h
  // ---- h = (CA/z)*O -> bf16, per-wave LDS round-trip into A-layout ----
  unsigned short* Hw = sm + XBT_OFF + wid * (WROWS * H_S);
#pragma unroll
  for (int r = 0; r < 4; ++r) {
    float rinv = CA / z_st[r];
#pragma unroll
    for (int dt = 0; dt < 8; ++dt)
      Hw[(q*4 + r) * H_S + dt*16 + c] = f2bf(Ofr[dt][r] * rinv);
  }
  // ---- G = h·W^T via MFMA; B[k=d][j] = W row-reads direct from global (d-contiguous) ----
  f32x4 G[8];
#pragma unroll
  for (int jt = 0; jt < 8; ++jt) G[jt] = (f32x4){0.f, 0.f, 0.f, 0.f};
#pragma unroll
  for (int ks = 0; ks < 4; ++ks) {
    bf16x8 hf = *(const bf16x8*)(Hw + c * H_S + ks*32 + q*8);
#pragma unroll
    for (int jt = 0; jt < 8; ++jt) {
      const float* wr = W + (size_t)(jt*16 + c) * DDIM + ks*32 + q*8;
      float4 a = *(const float4*)wr;
      float4 b = *(const float4*)(wr + 4);
      bf16x8 wf = pack8(a, b);
      G[jt] = __builtin_amdgcn_mfma_f32_16x16x32_bf16(hf, wf, G[jt], 0, 0, 0);
    }
  }
  // relu + output scale
#pragma unroll
  for (int jt = 0; jt < 8; ++jt) {
#pragma unroll
    for (int r = 0; r < 4; ++r) G[jt][r] = fmaxf(G[jt][r], 0.f) * CB;
  }
  // ---- LayerNorm over j (in-reg jt sum + 16-lane shfl), + residual, store ----
  float* Obt = Out + (size_t)bt * NNODES * DDIM;
#pragma unroll
  for (int r = 0; r < 4; ++r) {
    float s1 = 0.f, s2 = 0.f;
#pragma unroll
    for (int jt = 0; jt < 8; ++jt) { float v = G[jt][r]; s1 += v; s2 += v * v; }
#pragma unroll
    for (int off = 1; off < 16; off <<= 1) {
      s1 += __shfl_xor(s1, off, 64);
      s2 += __shfl_xor(s2, off, 64);
    }
    float mu = s1 * (1.f / 128.f);
    float va = s2 * (1.f / 128.f) - mu * mu;
    float rs = rsqrtf(va + LN_EPS);
    const float* xr = Xbt + (size_t)(grow + r) * DDIM;
    float* orow = Obt + (size_t)(grow + r) * DDIM;
#pragma unroll
    for (int jt = 0; jt < 8; ++jt) {
      int col = jt * 16 + c;
      orow[col] = (G[jt][r] - mu) * rs * gamma[col] + beta[col] + xr[col];
    }
  }
}

extern "C" void kernel_launch(void* const* d_in, const int* in_sizes, int n_in,
                              void* d_out, int out_size, void* d_ws, size_t ws_size,
                              hipStream_t stream) {
  const float* X     = (const float*)d_in[0];
  const float* A     = (const float*)d_in[1];
  const float* W     = (const float*)d_in[2];
  const float* gamma = (const float*)d_in[3];
  const float* beta  = (const float*)d_in[4];
  float* Out = (float*)d_out;
  dim3 grid(NNODES / BROWS, 64);   // 8 row-blocks x 64 (b,t) = 512 blocks = 2/CU
  hipLaunchKernelGGL(sdgcn_fused, grid, dim3(THREADS), 0, stream, X, A, W, gamma, beta, Out);
}

// Round 3
// 183.483 us; speedup vs baseline: 1.8906x; 1.1441x over previous
//
#include <hip/hip_runtime.h>

// SDGCN fused: per (b,t): S=X·X^T, softmax (diag-shift, no online max), A-mask,
// H=(A*P/Z*c_a)·X, relu(H·W^T)*c_b, LayerNorm, +X residual. bf16 MFMA 16x16x32.
// R3: removed online-softmax (shift by precomputed c_r=||x_r||^2, defer Z reduce
//     to epilogue -> no per-chunk shuffles/alpha); register-prefetch next chunk's
//     staging loads after sync1 to hide global latency.

#define NNODES 1024
#define DDIM   128
#define BROWS  128           // rows per block
#define WROWS  16            // rows per wave
#define MC     64            // m-chunk
#define NCHUNK (NNODES / MC) // 16
#define THREADS 512

#define CA 0.08838834764831845f   // 1/sqrt(128+1e-8)
#define CB 0.08838834764831845f   // 1/sqrt(128+1e-9)
#define LN_EPS 1e-5f

typedef __attribute__((ext_vector_type(8))) short bf16x8;
typedef __attribute__((ext_vector_type(4))) float f32x4;

// LDS layout (ushort units)
#define XBF_S 136                 // Xbf[64][136]  bf16 row-major chunk
#define XBT_S 72                  // XbT[128][72]  bf16 transposed chunk
#define P_S   72                  // P per wave [16][72]
#define H_S   136                 // h per wave [16][136] (reuses XbT+P region post-loop)
#define XBF_OFF 0                 // 64*136  = 8704 ushorts
#define XBT_OFF 8704              // 128*72  = 9216 ushorts
#define P_OFF   17920             // 8*16*72 = 9216 ushorts
#define SM_TOT  27136             // 54272 bytes -> 2 blocks/CU

__device__ __forceinline__ unsigned short f2bf(float f) {
  unsigned int u = __float_as_uint(f);
  u += 0x7FFFu + ((u >> 16) & 1u);     // RNE
  return (unsigned short)(u >> 16);
}

__device__ __forceinline__ bf16x8 pack8(float4 a, float4 b) {
  union { bf16x8 v; unsigned short u[8]; } pk;
  pk.u[0] = f2bf(a.x); pk.u[1] = f2bf(a.y); pk.u[2] = f2bf(a.z); pk.u[3] = f2bf(a.w);
  pk.u[4] = f2bf(b.x); pk.u[5] = f2bf(b.y); pk.u[6] = f2bf(b.z); pk.u[7] = f2bf(b.w);
  return pk.v;
}

__global__ __launch_bounds__(THREADS, 4)   // 4 waves/SIMD = 2 blocks/CU
void sdgcn_fused(const float* __restrict__ X, const float* __restrict__ A,
                 const float* __restrict__ W, const float* __restrict__ gamma,
                 const float* __restrict__ beta, float* __restrict__ Out) {
  const int bt   = blockIdx.y;
  const int row0 = blockIdx.x * BROWS;
  const int tid  = (int)threadIdx.x;
  const int wid  = tid >> 6;      // wave id 0..7
  const int lane = tid & 63;
  const int c    = lane & 15;     // 16-dim index within MFMA tile
  const int q    = lane >> 4;     // quad 0..3

  const float* Xbt = X + (size_t)bt * NNODES * DDIM;

  __shared__ __align__(16) unsigned short sm[SM_TOT];
  unsigned short* Pw = sm + P_OFF + wid * (WROWS * P_S);

  // ---- Q A-fragments + row sum-of-squares (fp32). A-layout: A[i=c][k=q*8+j] ----
  bf16x8 qfrag[4];
  float cn[4];                   // c_r = ||x_{4q+r}||^2 for this lane's C/D rows
  {
    const float* qrow = Xbt + (size_t)(row0 + wid * WROWS + c) * DDIM;
    float ss = 0.f;
#pragma unroll
    for (int ds = 0; ds < 4; ++ds) {
      const float* p = qrow + ds * 32 + q * 8;
      float4 a = *(const float4*)p;
      float4 b = *(const float4*)(p + 4);
      ss += a.x*a.x + a.y*a.y + a.z*a.z + a.w*a.w;
      ss += b.x*b.x + b.y*b.y + b.z*b.z + b.w*b.w;
      qfrag[ds] = pack8(a, b);
    }
    // reduce over the 4 q-replicas (lanes differing in bits 4,5) -> full row norm^2
    ss += __shfl_xor(ss, 16, 64);
    ss += __shfl_xor(ss, 32, 64);
    // lane q*16+cc holds ||row cc||^2; fetch rows 4q+r from same q-group
#pragma unroll
    for (int r = 0; r < 4; ++r)
      cn[r] = __shfl(ss, (lane & 48) + ((lane & 48) >> 2) + r, 64);
  }

  float z_st[4] = {0.f, 0.f, 0.f, 0.f};   // per-lane partial Z (reduced at end)
  f32x4 Ofr[8];   // O accumulator, C/D layout: row=4q+reg, col=dt*16+c
#pragma unroll
  for (int dt = 0; dt < 8; ++dt) Ofr[dt] = (f32x4){0.f, 0.f, 0.f, 0.f};

  const int grow = row0 + wid * WROWS + q * 4;   // +r gives global row for C/D rows

  // ---- staging register prefetch for chunk 0 ----
  const int sm_ = tid >> 5, sd4 = tid & 31;      // this thread's (m, d4) staging slot
  float4 stg[4];
#pragma unroll
  for (int k = 0; k < 4; ++k)
    stg[k] = *(const float4*)(Xbt + (size_t)(sm_ + k * 16) * DDIM + sd4 * 4);

  for (int ch = 0; ch < NCHUNK; ++ch) {
    const int m0 = ch * MC;
    // ---- write staged regs -> Xbf bf16 row-major ----
#pragma unroll
    for (int k = 0; k < 4; ++k) {
      float4 v = stg[k];
      unsigned int lo = (unsigned int)f2bf(v.x) | ((unsigned int)f2bf(v.y) << 16);
      unsigned int hi = (unsigned int)f2bf(v.z) | ((unsigned int)f2bf(v.w) << 16);
      *(uint2*)(sm + XBF_OFF + (sm_ + k * 16) * XBF_S + sd4 * 4) = make_uint2(lo, hi);
    }
    __syncthreads();   // Xbf ready; also fences prev-iter PV reads of XbT
    // ---- issue next chunk's staging loads (overlap with transpose+QK+PV) ----
    if (ch + 1 < NCHUNK) {
      const float* nx = Xbt + (size_t)(m0 + MC) * DDIM;
#pragma unroll
      for (int k = 0; k < 4; ++k)
        stg[k] = *(const float4*)(nx + (size_t)(sm_ + k * 16) * DDIM + sd4 * 4);
    }
    // ---- build XbT[d][m] from Xbf (b16 column reads 2-way/free, b128 writes) ----
#pragma unroll
    for (int k = 0; k < 2; ++k) {
      int task = tid + k * THREADS;          // 1024 tasks = 128 d x 8 m-octets
      int d = task & 127, m8 = task >> 7;
      int base = XBF_OFF + d;
      unsigned int w0 = (unsigned int)sm[base + (m8*8+0)*XBF_S] | ((unsigned int)sm[base + (m8*8+1)*XBF_S] << 16);
      unsigned int w1 = (unsigned int)sm[base + (m8*8+2)*XBF_S] | ((unsigned int)sm[base + (m8*8+3)*XBF_S] << 16);
      unsigned int w2 = (unsigned int)sm[base + (m8*8+4)*XBF_S] | ((unsigned int)sm[base + (m8*8+5)*XBF_S] << 16);
      unsigned int w3 = (unsigned int)sm[base + (m8*8+6)*XBF_S] | ((unsigned int)sm[base + (m8*8+7)*XBF_S] << 16);
      *(uint4*)(sm + XBT_OFF + d * XBT_S + m8 * 8) = make_uint4(w0, w1, w2, w3);
    }
    // ---- scores: S[16 rows][64 m] per wave; B[k=d][j=m] = Xbf row-reads ----
    f32x4 S[4];
#pragma unroll
    for (int mt = 0; mt < 4; ++mt) {
      f32x4 acc = (f32x4){0.f, 0.f, 0.f, 0.f};
#pragma unroll
      for (int ds = 0; ds < 4; ++ds) {
        bf16x8 bf = *(const bf16x8*)(sm + XBF_OFF + (mt*16 + c) * XBF_S + ds*32 + q*8);
        acc = __builtin_amdgcn_mfma_f32_16x16x32_bf16(qfrag[ds], bf, acc, 0, 0, 0);
      }
      S[mt] = acc;
    }
    // ---- prefetch adjacency values (global, L2-resident) ----
    float av[4][4];
#pragma unroll
    for (int r = 0; r < 4; ++r)
#pragma unroll
      for (int mt = 0; mt < 4; ++mt)
        av[r][mt] = A[(size_t)(grow + r) * NNODES + m0 + mt*16 + c];
    __syncthreads();   // XbT complete before PV reads
    // ---- softmax numerator: p = exp(S - c_r); Z accumulates linearly ----
#pragma unroll
    for (int r = 0; r < 4; ++r) {
      float zr = 0.f;
#pragma unroll
      for (int mt = 0; mt < 4; ++mt) {
        float p = __expf(S[mt][r] - cn[r]);
        zr += p;
        Pw[(q*4 + r) * P_S + mt*16 + c] = f2bf(p * av[r][mt]);
      }
      z_st[r] += zr;
    }
    // ---- PV: O += P·Xchunk ; A=P from Pw rows, B[k=m][j=d] from XbT ----
#pragma unroll
    for (int ks = 0; ks < 2; ++ks) {
      bf16x8 pf = *(const bf16x8*)(Pw + c * P_S + ks*32 + q*8);
#pragma unroll
      for (int dt = 0; dt < 8; ++dt) {
        bf16x8 vf = *(const bf16x8*)(sm + XBT_OFF + (dt*16 + c) * XBT_S + ks*32 + q*8);
        Ofr[dt] = __builtin_amdgcn_mfma_f32_16x16x32_bf16(pf, vf, Ofr[dt], 0, 0, 0);
      }
    }
  }

  // ---- finalize Z: reduce partials over the 16 c-lanes (once) ----
#pragma unroll
  for (int r = 0; r < 4; ++r) {
    float z = z_st[r];
#pragma unroll
    for (int off = 1; off < 16; off <<= 1) z += __shfl_xor(z, off, 64);
    z_st[r] = z;
  }

  __syncthreads();   // all PV reads done; reuse XbT+P region for h
  // ---- h = (CA/z)*O -> bf16, per-wave LDS round-trip into A-layout ----
  unsigned short* Hw = sm + XBT_OFF + wid * (WROWS * H_S);
#pragma unroll
  for (int r = 0; r < 4; ++r) {
    float rinv = CA / z_st[r];
#pragma unroll
    for (int dt = 0; dt < 8; ++dt)
      Hw[(q*4 + r) * H_S + dt*16 + c] = f2bf(Ofr[dt][r] * rinv);
  }
  // ---- G = h·W^T via MFMA; B[k=d][j] = W row-reads direct from global ----
  f32x4 G[8];
#pragma unroll
  for (int jt = 0; jt < 8; ++jt) G[jt] = (f32x4){0.f, 0.f, 0.f, 0.f};
#pragma unroll
  for (int ks = 0; ks < 4; ++ks) {
    bf16x8 hf = *(const bf16x8*)(Hw + c * H_S + ks*32 + q*8);
#pragma unroll
    for (int jt = 0; jt < 8; ++jt) {
      const float* wr = W + (size_t)(jt*16 + c) * DDIM + ks*32 + q*8;
      float4 a = *(const float4*)wr;
      float4 b = *(const float4*)(wr + 4);
      bf16x8 wf = pack8(a, b);
      G[jt] = __builtin_amdgcn_mfma_f32_16x16x32_bf16(hf, wf, G[jt], 0, 0, 0);
    }
  }
  // relu + output scale
#pragma unroll
  for (int jt = 0; jt < 8; ++jt) {
#pragma unroll
    for (int r = 0; r < 4; ++r) G[jt][r] = fmaxf(G[jt][r], 0.f) * CB;
  }
  // ---- LayerNorm over j (in-reg jt sum + 16-lane shfl), + residual, store ----
  float* Obt = Out + (size_t)bt * NNODES * DDIM;
#pragma unroll
  for (int r = 0; r < 4; ++r) {
    float s1 = 0.f, s2 = 0.f;
#pragma unroll
    for (int jt = 0; jt < 8; ++jt) { float v = G[jt][r]; s1 += v; s2 += v * v; }
#pragma unroll
    for (int off = 1; off < 16; off <<= 1) {
      s1 += __shfl_xor(s1, off, 64);
      s2 += __shfl_xor(s2, off, 64);
    }
    float mu = s1 * (1.f / 128.f);
    float va = s2 * (1.f / 128.f) - mu * mu;
    float rs = rsqrtf(va + LN_EPS);
    const float* xr = Xbt + (size_t)(grow + r) * DDIM;
    float* orow = Obt + (size_t)(grow + r) * DDIM;
#pragma unroll
    for (int jt = 0; jt < 8; ++jt) {
      int col = jt * 16 + c;
      orow[col] = (G[jt][r] - mu) * rs * gamma[col] + beta[col] + xr[col];
    }
  }
}

extern "C" void kernel_launch(void* const* d_in, const int* in_sizes, int n_in,
                              void* d_out, int out_size, void* d_ws, size_t ws_size,
                              hipStream_t stream) {
  const float* X     = (const float*)d_in[0];
  const float* A     = (const float*)d_in[1];
  const float* W     = (const float*)d_in[2];
  const float* gamma = (const float*)d_in[3];
  const float* beta  = (const float*)d_in[4];
  float* Out = (float*)d_out;
  dim3 grid(NNODES / BROWS, 64);   // 8 row-blocks x 64 (b,t) = 512 blocks = 2/CU
  hipLaunchKernelGGL(sdgcn_fused, grid, dim3(THREADS), 0, stream, X, A, W, gamma, beta, Out);
}

// Round 4
// 181.443 us; speedup vs baseline: 1.9119x; 1.0112x over previous
//
#include <hip/hip_runtime.h>

// SDGCN fused: per (b,t): S=X·X^T, softmax (diag-shift c_r=||x_r||^2, linear Z),
// A-mask, H=(A*P/Z*c_a)·X, relu(H·W^T)*c_b, LayerNorm, +X residual. bf16 MFMA.
// R4: (1) A-prefetch hoisted before transpose (covered by transpose+QK);
//     (2) grid transposed (bt fast) so consecutive blocks share A row-slice in L2;
//     (3) XOR col-swizzle on P and H LDS tiles (kills u16 scatter-write 4-way
//         bank conflicts; reader permutes q->q^2 within ks-half, b128 stays aligned).

#define NNODES 1024
#define DDIM   128
#define BROWS  128           // rows per block
#define WROWS  16            // rows per wave
#define MC     64            // m-chunk
#define NCHUNK (NNODES / MC) // 16
#define THREADS 512

#define CA 0.08838834764831845f   // 1/sqrt(128+1e-8)
#define CB 0.08838834764831845f   // 1/sqrt(128+1e-9)
#define LN_EPS 1e-5f

typedef __attribute__((ext_vector_type(8))) short bf16x8;
typedef __attribute__((ext_vector_type(4))) float f32x4;

// LDS layout (ushort units)
#define XBF_S 136                 // Xbf[64][136]  bf16 row-major chunk (17x16B lines: b128-free)
#define XBT_S 72                  // XbT[128][72]  bf16 transposed chunk (9x16B lines: b128-free)
#define P_S   72                  // P per wave [16][72], col-swizzled
#define H_S   136                 // h per wave [16][136], col-swizzled (reuses XbT+P region)
#define XBF_OFF 0                 // 64*136  = 8704 ushorts
#define XBT_OFF 8704              // 128*72  = 9216 ushorts
#define P_OFF   17920             // 8*16*72 = 9216 ushorts
#define SM_TOT  27136             // 54272 bytes -> 2 blocks/CU

__device__ __forceinline__ unsigned short f2bf(float f) {
  unsigned int u = __float_as_uint(f);
  u += 0x7FFFu + ((u >> 16) & 1u);     // RNE
  return (unsigned short)(u >> 16);
}

__device__ __forceinline__ bf16x8 pack8(float4 a, float4 b) {
  union { bf16x8 v; unsigned short u[8]; } pk;
  pk.u[0] = f2bf(a.x); pk.u[1] = f2bf(a.y); pk.u[2] = f2bf(a.z); pk.u[3] = f2bf(a.w);
  pk.u[4] = f2bf(b.x); pk.u[5] = f2bf(b.y); pk.u[6] = f2bf(b.z); pk.u[7] = f2bf(b.w);
  return pk.v;
}

__global__ __launch_bounds__(THREADS, 4)   // 4 waves/SIMD = 2 blocks/CU
void sdgcn_fused(const float* __restrict__ X, const float* __restrict__ A,
                 const float* __restrict__ W, const float* __restrict__ gamma,
                 const float* __restrict__ beta, float* __restrict__ Out) {
  const int bt   = blockIdx.x;                 // fast axis: blocks sharing A-slice adjacent
  const int row0 = blockIdx.y * BROWS;
  const int tid  = (int)threadIdx.x;
  const int wid  = tid >> 6;      // wave id 0..7
  const int lane = tid & 63;
  const int c    = lane & 15;     // 16-dim index within MFMA tile
  const int q    = lane >> 4;     // quad 0..3

  const float* Xbt = X + (size_t)bt * NNODES * DDIM;

  __shared__ __align__(16) unsigned short sm[SM_TOT];
  unsigned short* Pw = sm + P_OFF + wid * (WROWS * P_S);

  // col-swizzle constants: element [row][col] stored at col ^ (16*((row>>3)&1))
  const int wswz = 16 * (q >> 1);              // writer: row = 4q+r -> (row>>3)&1 = q>>1
  const int rswz = 16 * ((c >> 3) & 1);        // reader: row = c

  // ---- Q A-fragments + row sum-of-squares (fp32). A-layout: A[i=c][k=q*8+j] ----
  bf16x8 qfrag[4];
  float cn[4];                   // c_r = ||x_{4q+r}||^2 for this lane's C/D rows
  {
    const float* qrow = Xbt + (size_t)(row0 + wid * WROWS + c) * DDIM;
    float ss = 0.f;
#pragma unroll
    for (int ds = 0; ds < 4; ++ds) {
      const float* p = qrow + ds * 32 + q * 8;
      float4 a = *(const float4*)p;
      float4 b = *(const float4*)(p + 4);
      ss += a.x*a.x + a.y*a.y + a.z*a.z + a.w*a.w;
      ss += b.x*b.x + b.y*b.y + b.z*b.z + b.w*b.w;
      qfrag[ds] = pack8(a, b);
    }
    ss += __shfl_xor(ss, 16, 64);
    ss += __shfl_xor(ss, 32, 64);
#pragma unroll
    for (int r = 0; r < 4; ++r)
      cn[r] = __shfl(ss, (lane & 48) + ((lane & 48) >> 2) + r, 64);
  }

  float z_st[4] = {0.f, 0.f, 0.f, 0.f};   // per-lane partial Z (reduced at end)
  f32x4 Ofr[8];   // O accumulator, C/D layout: row=4q+reg, col=dt*16+c
#pragma unroll
  for (int dt = 0; dt < 8; ++dt) Ofr[dt] = (f32x4){0.f, 0.f, 0.f, 0.f};

  const int grow = row0 + wid * WROWS + q * 4;   // +r gives global row for C/D rows

  // ---- staging register prefetch for chunk 0 ----
  const int sm_ = tid >> 5, sd4 = tid & 31;      // this thread's (m, d4) staging slot
  float4 stg[4];
#pragma unroll
  for (int k = 0; k < 4; ++k)
    stg[k] = *(const float4*)(Xbt + (size_t)(sm_ + k * 16) * DDIM + sd4 * 4);

  for (int ch = 0; ch < NCHUNK; ++ch) {
    const int m0 = ch * MC;
    // ---- write staged regs -> Xbf bf16 row-major ----
#pragma unroll
    for (int k = 0; k < 4; ++k) {
      float4 v = stg[k];
      unsigned int lo = (unsigned int)f2bf(v.x) | ((unsigned int)f2bf(v.y) << 16);
      unsigned int hi = (unsigned int)f2bf(v.z) | ((unsigned int)f2bf(v.w) << 16);
      *(uint2*)(sm + XBF_OFF + (sm_ + k * 16) * XBF_S + sd4 * 4) = make_uint2(lo, hi);
    }
    __syncthreads();   // Xbf ready; also fences prev-iter PV reads of XbT
    // ---- issue next chunk's staging loads (overlap transpose+QK+PV) ----
    if (ch + 1 < NCHUNK) {
      const float* nx = Xbt + (size_t)(m0 + MC) * DDIM;
#pragma unroll
      for (int k = 0; k < 4; ++k)
        stg[k] = *(const float4*)(nx + (size_t)(sm_ + k * 16) * DDIM + sd4 * 4);
    }
    // ---- prefetch adjacency (hoisted: covered by transpose + QK below) ----
    float av[4][4];
#pragma unroll
    for (int r = 0; r < 4; ++r)
#pragma unroll
      for (int mt = 0; mt < 4; ++mt)
        av[r][mt] = A[(size_t)(grow + r) * NNODES + m0 + mt*16 + c];
    // ---- build XbT[d][m] from Xbf (b16 column reads 2-way/free, b128 writes) ----
#pragma unroll
    for (int k = 0; k < 2; ++k) {
      int task = tid + k * THREADS;          // 1024 tasks = 128 d x 8 m-octets
      int d = task & 127, m8 = task >> 7;
      int base = XBF_OFF + d;
      unsigned int w0 = (unsigned int)sm[base + (m8*8+0)*XBF_S] | ((unsigned int)sm[base + (m8*8+1)*XBF_S] << 16);
      unsigned int w1 = (unsigned int)sm[base + (m8*8+2)*XBF_S] | ((unsigned int)sm[base + (m8*8+3)*XBF_S] << 16);
      unsigned int w2 = (unsigned int)sm[base + (m8*8+4)*XBF_S] | ((unsigned int)sm[base + (m8*8+5)*XBF_S] << 16);
      unsigned int w3 = (unsigned int)sm[base + (m8*8+6)*XBF_S] | ((unsigned int)sm[base + (m8*8+7)*XBF_S] << 16);
      *(uint4*)(sm + XBT_OFF + d * XBT_S + m8 * 8) = make_uint4(w0, w1, w2, w3);
    }
    // ---- scores: S[16 rows][64 m] per wave; B[k=d][j=m] = Xbf row-reads ----
    f32x4 S[4];
#pragma unroll
    for (int mt = 0; mt < 4; ++mt) {
      f32x4 acc = (f32x4){0.f, 0.f, 0.f, 0.f};
#pragma unroll
      for (int ds = 0; ds < 4; ++ds) {
        bf16x8 bf = *(const bf16x8*)(sm + XBF_OFF + (mt*16 + c) * XBF_S + ds*32 + q*8);
        acc = __builtin_amdgcn_mfma_f32_16x16x32_bf16(qfrag[ds], bf, acc, 0, 0, 0);
      }
      S[mt] = acc;
    }
    __syncthreads();   // XbT complete before PV reads
    // ---- softmax numerator: p = exp(S - c_r); Z accumulates linearly.
    //      P write col-swizzled: [4q+r][ (mt*16+c) ^ wswz ] -> conflict-free banks
#pragma unroll
    for (int r = 0; r < 4; ++r) {
      float zr = 0.f;
#pragma unroll
      for (int mt = 0; mt < 4; ++mt) {
        float p = __expf(S[mt][r] - cn[r]);
        zr += p;
        Pw[(q*4 + r) * P_S + (((mt*16) ^ wswz) + c)] = f2bf(p * av[r][mt]);
      }
      z_st[r] += zr;
    }
    // ---- PV: O += P·Xchunk ; A=P rows (swizzle-corrected read), B from XbT ----
#pragma unroll
    for (int ks = 0; ks < 2; ++ks) {
      bf16x8 pf = *(const bf16x8*)(Pw + c * P_S + (((ks*32 + q*8) ^ rswz)));
#pragma unroll
      for (int dt = 0; dt < 8; ++dt) {
        bf16x8 vf = *(const bf16x8*)(sm + XBT_OFF + (dt*16 + c) * XBT_S + ks*32 + q*8);
        Ofr[dt] = __builtin_amdgcn_mfma_f32_16x16x32_bf16(pf, vf, Ofr[dt], 0, 0, 0);
      }
    }
  }

  // ---- finalize Z: reduce partials over the 16 c-lanes (once) ----
#pragma unroll
  for (int r = 0; r < 4; ++r) {
    float z = z_st[r];
#pragma unroll
    for (int off = 1; off < 16; off <<= 1) z += __shfl_xor(z, off, 64);
    z_st[r] = z;
  }

  __syncthreads();   // all PV reads done; reuse XbT+P region for h
  // ---- h = (CA/z)*O -> bf16, per-wave LDS round-trip into A-layout (swizzled) ----
  unsigned short* Hw = sm + XBT_OFF + wid * (WROWS * H_S);
#pragma unroll
  for (int r = 0; r < 4; ++r) {
    float rinv = CA / z_st[r];
#pragma unroll
    for (int dt = 0; dt < 8; ++dt)
      Hw[(q*4 + r) * H_S + (((dt*16) ^ wswz) + c)] = f2bf(Ofr[dt][r] * rinv);
  }
  // ---- G = h·W^T via MFMA; B[k=d][j] = W row-reads direct from global ----
  f32x4 G[8];
#pragma unroll
  for (int jt = 0; jt < 8; ++jt) G[jt] = (f32x4){0.f, 0.f, 0.f, 0.f};
#pragma unroll
  for (int ks = 0; ks < 4; ++ks) {
    bf16x8 hf = *(const bf16x8*)(Hw + c * H_S + (((ks*32 + q*8) ^ rswz)));
#pragma unroll
    for (int jt = 0; jt < 8; ++jt) {
      const float* wr = W + (size_t)(jt*16 + c) * DDIM + ks*32 + q*8;
      float4 a = *(const float4*)wr;
      float4 b = *(const float4*)(wr + 4);
      bf16x8 wf = pack8(a, b);
      G[jt] = __builtin_amdgcn_mfma_f32_16x16x32_bf16(hf, wf, G[jt], 0, 0, 0);
    }
  }
  // relu + output scale
#pragma unroll
  for (int jt = 0; jt < 8; ++jt) {
#pragma unroll
    for (int r = 0; r < 4; ++r) G[jt][r] = fmaxf(G[jt][r], 0.f) * CB;
  }
  // ---- LayerNorm over j (in-reg jt sum + 16-lane shfl), + residual, store ----
  float* Obt = Out + (size_t)bt * NNODES * DDIM;
#pragma unroll
  for (int r = 0; r < 4; ++r) {
    float s1 = 0.f, s2 = 0.f;
#pragma unroll
    for (int jt = 0; jt < 8; ++jt) { float v = G[jt][r]; s1 += v; s2 += v * v; }
#pragma unroll
    for (int off = 1; off < 16; off <<= 1) {
      s1 += __shfl_xor(s1, off, 64);
      s2 += __shfl_xor(s2, off, 64);
    }
    float mu = s1 * (1.f / 128.f);
    float va = s2 * (1.f / 128.f) - mu * mu;
    float rs = rsqrtf(va + LN_EPS);
    const float* xr = Xbt + (size_t)(grow + r) * DDIM;
    float* orow = Obt + (size_t)(grow + r) * DDIM;
#pragma unroll
    for (int jt = 0; jt < 8; ++jt) {
      int col = jt * 16 + c;
      orow[col] = (G[jt][r] - mu) * rs * gamma[col] + beta[col] + xr[col];
    }
  }
}

extern "C" void kernel_launch(void* const* d_in, const int* in_sizes, int n_in,
                              void* d_out, int out_size, void* d_ws, size_t ws_size,
                              hipStream_t stream) {
  const float* X     = (const float*)d_in[0];
  const float* A     = (const float*)d_in[1];
  const float* W     = (const float*)d_in[2];
  const float* gamma = (const float*)d_in[3];
  const float* beta  = (const float*)d_in[4];
  float* Out = (float*)d_out;
  dim3 grid(64, NNODES / BROWS);   // bt fast, 8 row-blocks slow
  hipLaunchKernelGGL(sdgcn_fused, grid, dim3(THREADS), 0, stream, X, A, W, gamma, beta, Out);
}